// Round 9
// baseline (910.758 us; speedup 1.0000x reference)
//
#include <hip/hip_runtime.h>
#include <stdint.h>

#define NP 25088   // B * oH * oW = 8*56*56
#define DD 576     // 64 * 3 * 3
#define KC 256     // centroids

// ---------------- unfold: x[8,64,56,56] -> P[n][d] (patch-major) -------------
__global__ __launch_bounds__(256) void unfold_kernel(const float* __restrict__ x,
                                                     float* __restrict__ P) {
  const int n0 = blockIdx.x * 16;                // 16 patches per block
#pragma unroll 1
  for (int rr = 0; rr < 36; ++rr) {              // 16*576/256
    const unsigned idx = rr * 256 + threadIdx.x; // 0..9215
    const int n = n0 + (int)(idx / 576u);
    const int d = (int)(idx % 576u);
    const int c = d / 9, r = d % 9;
    const int di = r / 3 - 1, dj = r % 3 - 1;
    const int b = n / 3136, hw = n % 3136;
    const int h = hw / 56 + di, w = hw % 56 + dj;
    float v = 0.0f;
    if (h >= 0 && h < 56 && w >= 0 && w < 56)
      v = x[(((size_t)b * 64 + c) * 56 + h) * 56 + w];
    P[(size_t)n * DD + d] = v;                   // consecutive tid -> consecutive d
  }
}

// ---------------- nearest: thread = centroid k, block = 16 patches -----------
// R8 post-mortem: VGPR=28/SGPR=64 -> compiler allocated ZERO prefetch depth;
// each chunk serialized on its own s_load/global chain (real VALU duty ~31%).
// THIS ROUND: explicit pipeline depth.
//  - A staged in LDS per 288-d half (18 KB; 4 barriers total, main loop
//    barrier-free). Inner A reads are wave-uniform ds_read_b128 broadcasts
//    (conflict-free, deduped across waves, hoistable: no dependencies).
//  - B double-buffered in named float4 regs: next chunk's 4 loads issued
//    before the current 512-instr VALU body (L2 latency ~300cy << 1024cy).
//  - launch_bounds(256,6): 6 blocks/CU (LDS 114 KB), 24 waves/CU, grid 1568
//    vs 1536 resident -> 2% tail.
#define STEP(mm, ACC) do {                                          \
    const float4 a0 = *(const float4*)&Alds[mm][cb];                \
    const float4 a1 = *(const float4*)&Alds[mm][cb + 4];            \
    const float4 a2 = *(const float4*)&Alds[mm][cb + 8];            \
    const float4 a3 = *(const float4*)&Alds[mm][cb + 12];           \
    const float s_ =                                                \
      ((((fabsf(a0.x - vb0.x) + fabsf(a0.y - vb0.y)) +              \
         (fabsf(a0.z - vb0.z) + fabsf(a0.w - vb0.w))) +             \
        ((fabsf(a1.x - vb1.x) + fabsf(a1.y - vb1.y)) +              \
         (fabsf(a1.z - vb1.z) + fabsf(a1.w - vb1.w)))) +            \
       (((fabsf(a2.x - vb2.x) + fabsf(a2.y - vb2.y)) +              \
         (fabsf(a2.z - vb2.z) + fabsf(a2.w - vb2.w))) +             \
        ((fabsf(a3.x - vb3.x) + fabsf(a3.y - vb3.y)) +              \
         (fabsf(a3.z - vb3.z) + fabsf(a3.w - vb3.w)))));            \
    ACC += s_;                                                      \
  } while (0)

#define REDUCE(mm, V) do {                                          \
    float bd_ = (V); int bk_ = tid;                                 \
    _Pragma("unroll")                                               \
    for (int off_ = 1; off_ < 64; off_ <<= 1) {                     \
      const float od_ = __shfl_xor(bd_, off_, 64);                  \
      const int ok_ = __shfl_xor(bk_, off_, 64);                    \
      if (od_ < bd_ || (od_ == bd_ && ok_ < bk_)) { bd_ = od_; bk_ = ok_; } \
    }                                                               \
    if (lane == 0) { sd[wv][mm] = bd_; si[wv][mm] = bk_; }          \
  } while (0)

__global__ __launch_bounds__(256, 6) void nearest_kernel(const float* __restrict__ A,
                                                         const float* __restrict__ C,
                                                         int* __restrict__ idx_out) {
  __shared__ __align__(16) float Alds[16][288];  // 18 KB: one 288-d half
  __shared__ float sd[4][16];
  __shared__ int si[4][16];

  const int tid = threadIdx.x;                 // = centroid k (0..255)
  const int lane = tid & 63, wv = tid >> 6;
  const int m0 = blockIdx.x * 16;              // 16 patches per block

  const float* bp = C + (size_t)tid * DD;      // per-lane centroid row

  // B current-chunk regs + accumulators: named float4 only (arrays => scratch)
  float4 vb0 = *(const float4*)(bp);
  float4 vb1 = *(const float4*)(bp + 4);
  float4 vb2 = *(const float4*)(bp + 8);
  float4 vb3 = *(const float4*)(bp + 12);
  float4 acc0, acc1, acc2, acc3;
  acc0 = acc1 = acc2 = acc3 = make_float4(0.f, 0.f, 0.f, 0.f);

#pragma unroll 1
  for (int half = 0; half < 2; ++half) {
    __syncthreads();                           // prior half's reads complete
    // stage 16 rows x 288 cols of A (coalesced 64B row segments)
#pragma unroll
    for (int q = tid; q < 1152; q += 256) {    // 1152 float4s
      const int row = q / 72, col = (q % 72) * 4;
      *(float4*)&Alds[row][col] =
          *(const float4*)(A + (size_t)(m0 + row) * DD + half * 288 + col);
    }
    __syncthreads();
#pragma unroll 1
    for (int ch = 0; ch < 18; ++ch) {          // 18 * 16 = 288 d's per half
      const int g = half * 18 + ch;
      const int pf = (g < 35) ? 16 : 0;        // clamp last prefetch (k=255 OOB)
      const float4 nb0 = *(const float4*)(bp + pf);
      const float4 nb1 = *(const float4*)(bp + pf + 4);
      const float4 nb2 = *(const float4*)(bp + pf + 8);
      const float4 nb3 = *(const float4*)(bp + pf + 12);
      const int cb = ch * 16;
      STEP(0,  acc0.x); STEP(1,  acc0.y); STEP(2,  acc0.z); STEP(3,  acc0.w);
      STEP(4,  acc1.x); STEP(5,  acc1.y); STEP(6,  acc1.z); STEP(7,  acc1.w);
      STEP(8,  acc2.x); STEP(9,  acc2.y); STEP(10, acc2.z); STEP(11, acc2.w);
      STEP(12, acc3.x); STEP(13, acc3.y); STEP(14, acc3.z); STEP(15, acc3.w);
      vb0 = nb0; vb1 = nb1; vb2 = nb2; vb3 = nb3;
      bp += 16;
    }
  }

  REDUCE(0,  acc0.x); REDUCE(1,  acc0.y); REDUCE(2,  acc0.z); REDUCE(3,  acc0.w);
  REDUCE(4,  acc1.x); REDUCE(5,  acc1.y); REDUCE(6,  acc1.z); REDUCE(7,  acc1.w);
  REDUCE(8,  acc2.x); REDUCE(9,  acc2.y); REDUCE(10, acc2.z); REDUCE(11, acc2.w);
  REDUCE(12, acc3.x); REDUCE(13, acc3.y); REDUCE(14, acc3.z); REDUCE(15, acc3.w);

  __syncthreads();
  if (tid < 16) {
    float bd = sd[0][tid];
    int bk = si[0][tid];
#pragma unroll
    for (int w = 1; w < 4; ++w) {              // ascending wave => ascending k;
      const float od = sd[w][tid];             // strict < keeps lowest k on ties
      if (od < bd) { bd = od; bk = si[w][tid]; }
    }
    idx_out[m0 + tid] = bk;
  }
}

// ---------------- residual in place: P[n][d] -= C1[idx1[n]][d] ---------------
__global__ __launch_bounds__(256) void resid_kernel(float* __restrict__ P,
                                                    const float* __restrict__ C1,
                                                    const int* __restrict__ idx1) {
  const int n0 = blockIdx.x * 16;
#pragma unroll 1
  for (int rr = 0; rr < 9; ++rr) {             // 16*144 float4s / 256 threads
    const unsigned q = rr * 256 + threadIdx.x; // 0..2303
    const int n = n0 + (int)(q / 144u);
    const int dq = (int)(q % 144u);            // float4 index within row
    const int k = idx1[n];
    float4* pp = (float4*)(P + (size_t)n * DD + dq * 4);
    const float4 pv = *pp;
    const float4 cv = *(const float4*)(C1 + (size_t)k * DD + dq * 4);
    *pp = make_float4(pv.x - cv.x, pv.y - cv.y, pv.z - cv.z, pv.w - cv.w);
  }
}

// ---------------- BN stats: per-channel sum & sumsq of LUT outputs -----------
__global__ __launch_bounds__(256) void stats_kernel(const int* __restrict__ idx1,
                                                    const int* __restrict__ idx2,
                                                    const float* __restrict__ dotc,
                                                    const float* __restrict__ dotrc,
                                                    float* __restrict__ gsum,
                                                    float* __restrict__ gsq) {
  __shared__ float ssum[4][128], ssq[4][128];
  const int tid = threadIdx.x, lane = tid & 63, wv = tid >> 6;
  const int wid = blockIdx.x * 4 + wv;           // 0..511
  float s0 = 0.f, s1 = 0.f, q0 = 0.f, q1 = 0.f;
  for (int n = wid; n < NP; n += 512) {          // 25088 = 512*49
    const int k1 = idx1[n], k2 = idx2[n];
    const float2 u = ((const float2*)(dotc + (size_t)k1 * 128))[lane];
    const float2 v = ((const float2*)(dotrc + (size_t)k2 * 128))[lane];
    const float x0 = u.x + v.x, x1 = u.y + v.y;
    s0 += x0; s1 += x1; q0 += x0 * x0; q1 += x1 * x1;
  }
  ssum[wv][lane * 2] = s0; ssum[wv][lane * 2 + 1] = s1;
  ssq[wv][lane * 2] = q0;  ssq[wv][lane * 2 + 1] = q1;
  __syncthreads();
  if (tid < 128) {
    const float s = ssum[0][tid] + ssum[1][tid] + ssum[2][tid] + ssum[3][tid];
    const float q = ssq[0][tid] + ssq[1][tid] + ssq[2][tid] + ssq[3][tid];
    atomicAdd(&gsum[tid], s);
    atomicAdd(&gsq[tid], q);
  }
}

__global__ void finalize_kernel(const float* __restrict__ gsum,
                                const float* __restrict__ gsq,
                                const float* __restrict__ gamma,
                                const float* __restrict__ beta,
                                float* __restrict__ scalev,
                                float* __restrict__ shiftv) {
  const int c = threadIdx.x;                     // 128
  const float mean = gsum[c] * (1.0f / NP);
  const float var = gsq[c] * (1.0f / NP) - mean * mean;
  const float inv = rsqrtf(var + 1e-5f);
  const float sc = gamma[c] * inv;
  scalev[c] = sc;
  shiftv[c] = beta[c] - mean * sc;
}

// ---------------- output: LUT gather + affine BN + [B,C,H,W] store -----------
__global__ __launch_bounds__(256) void output_kernel(const int* __restrict__ idx1,
                                                     const int* __restrict__ idx2,
                                                     const float* __restrict__ dotc,
                                                     const float* __restrict__ dotrc,
                                                     const float* __restrict__ scalev,
                                                     const float* __restrict__ shiftv,
                                                     float* __restrict__ out) {
  __shared__ float vals[64][128];                // [n-local][c]  32 KB
  const int tid = threadIdx.x, lane = tid & 63, wv = tid >> 6;
  const int blk = blockIdx.x;                    // 392 = 8 * 49
  const int b = blk / 49, hw0 = (blk % 49) * 64;
  const int n0 = b * 3136 + hw0;
  const float sc0 = scalev[lane * 2], sc1 = scalev[lane * 2 + 1];
  const float sh0 = shiftv[lane * 2], sh1 = shiftv[lane * 2 + 1];
  for (int t = 0; t < 16; ++t) {
    const int nn = wv * 16 + t;
    const int n = n0 + nn;
    const int k1 = idx1[n], k2 = idx2[n];
    const float2 u = ((const float2*)(dotc + (size_t)k1 * 128))[lane];
    const float2 v = ((const float2*)(dotrc + (size_t)k2 * 128))[lane];
    *(float2*)&vals[nn][lane * 2] =
        make_float2(sc0 * (u.x + v.x) + sh0, sc1 * (u.y + v.y) + sh1);
  }
  __syncthreads();
  const int c = tid >> 1, half = tid & 1;
  float* op = out + ((size_t)b * 128 + c) * 3136 + hw0 + half * 32;
#pragma unroll
  for (int i = 0; i < 32; i += 4) {
    float4 w4;
    w4.x = vals[half * 32 + i + 0][c];
    w4.y = vals[half * 32 + i + 1][c];
    w4.z = vals[half * 32 + i + 2][c];
    w4.w = vals[half * 32 + i + 3][c];
    *(float4*)(op + i) = w4;
  }
}

extern "C" void kernel_launch(void* const* d_in, const int* in_sizes, int n_in,
                              void* d_out, int out_size, void* d_ws, size_t ws_size,
                              hipStream_t stream) {
  const float* x     = (const float*)d_in[0];
  const float* cent  = (const float*)d_in[1];
  const float* rcent = (const float*)d_in[2];
  const float* dotc  = (const float*)d_in[3];
  const float* dotrc = (const float*)d_in[4];
  const float* gamma = (const float*)d_in[5];
  const float* beta  = (const float*)d_in[6];
  float* out = (float*)d_out;

  // workspace layout (~58 MB)
  float* P   = (float*)d_ws;                 // [25088][576] patch-major
  int* idx1  = (int*)(P + (size_t)NP * DD);
  int* idx2  = idx1 + NP;
  float* gsum   = (float*)(idx2 + NP);       // [128]
  float* gsq    = gsum + 128;                // [128]
  float* scalev = gsq + 128;                 // [128]
  float* shiftv = scalev + 128;              // [128]

  unfold_kernel<<<1568, 256, 0, stream>>>(x, P);
  nearest_kernel<<<1568, 256, 0, stream>>>(P, cent, idx1);
  resid_kernel<<<1568, 256, 0, stream>>>(P, cent, idx1);
  nearest_kernel<<<1568, 256, 0, stream>>>(P, rcent, idx2);
  hipMemsetAsync(gsum, 0, 256 * sizeof(float), stream);
  stats_kernel<<<128, 256, 0, stream>>>(idx1, idx2, dotc, dotrc, gsum, gsq);
  finalize_kernel<<<1, 128, 0, stream>>>(gsum, gsq, gamma, beta, scalev, shiftv);
  output_kernel<<<392, 256, 0, stream>>>(idx1, idx2, dotc, dotrc, scalev, shiftv, out);
}